// Round 1
// baseline (17.246 us; speedup 1.0000x reference)
//
#include <hip/hip_runtime.h>
#include <math.h>

#define BB 4
#define NN 64
#define TT 80
#define DD 6
#define KK 5
#define BUFFER_DIST 0.2f
#define DECAY 0.9f

__global__ __launch_bounds__(256) void collision_kernel(
    const float* __restrict__ Y,
    const float* __restrict__ length,
    const float* __restrict__ width,
    float* __restrict__ partial) // [BB*TT]
{
    const int blk = blockIdx.x;        // b*TT + t
    const int b = blk / TT;
    const int t = blk % TT;
    const int tid = threadIdx.x;

    __shared__ float2 w[KK][NN];   // (wx, wy) per disk k, agent n
    __shared__ float rad[NN];

    if (tid < NN) {
        const int n = tid;
        const float* y = Y + (((size_t)(b * NN + n) * TT + t) * DD);
        const float px  = y[0];
        const float py  = y[1];
        const float yaw = y[4];
        const float c = cosf(yaw);
        const float s = sinf(yaw);
        const float L = length[b * NN + n];
        const float W = width[b * NN + n];
        const float ar = 0.5f * W;
        rad[n] = ar;
        const float cmin = -(0.5f * L) + ar;
        const float cmax =  (0.5f * L) - ar;
        const float span = cmax - cmin;
        #pragma unroll
        for (int k = 0; k < KK; ++k) {
            const float frac = (float)k / (float)(KK - 1);
            const float cx = cmin + span * frac;
            // wx = cx*c + px ; wy = -cx*s + py  (matches reference signs)
            w[k][n] = make_float2(fmaf(cx, c, px), fmaf(-cx, s, py));
        }
    }
    __syncthreads();

    float sum = 0.0f;
    // 64*64 = 4096 (i,j) pairs; 256 threads -> 16 iters; p = iter*256 + tid
    // i = p>>6 is wave-uniform (LDS broadcast); j = p&63 is stride-1.
    #pragma unroll 1
    for (int iter = 0; iter < 16; ++iter) {
        const int p = iter * 256 + tid;
        const int i = p >> 6;
        const int j = p & 63;
        float2 wi[KK];
        #pragma unroll
        for (int k = 0; k < KK; ++k) wi[k] = w[k][i];
        float mind2 = 3.4e38f;
        #pragma unroll
        for (int l = 0; l < KK; ++l) {
            const float2 wj = w[l][j];
            #pragma unroll
            for (int k = 0; k < KK; ++k) {
                const float dx = wi[k].x - wj.x;
                const float dy = wi[k].y - wj.y;
                const float d2 = fmaf(dx, dx, dy * dy);
                mind2 = fminf(mind2, d2);
            }
        }
        const float dist = (mind2 > 1e-12f) ? sqrtf(mind2) : 0.0f;
        const float pd = rad[i] + rad[j] + BUFFER_DIST;
        const float pen = 1.0f - dist / pd;
        const bool valid = (i != j) && (dist <= pd);
        sum += valid ? pen : 0.0f;
    }

    // wave reduce (64 lanes) then cross-wave via LDS
    #pragma unroll
    for (int off = 32; off > 0; off >>= 1)
        sum += __shfl_down(sum, off, 64);
    __shared__ float wsum[4];
    const int wave = tid >> 6;
    const int lane = tid & 63;
    if (lane == 0) wsum[wave] = sum;
    __syncthreads();
    if (tid == 0) {
        const float tot = wsum[0] + wsum[1] + wsum[2] + wsum[3];
        // exp_w[t] = 0.9^t / sum_{u<T} 0.9^u ; geometric closed form
        const float denom = (1.0f - powf(DECAY, (float)TT)) / (1.0f - DECAY);
        const float wgt = powf(DECAY, (float)t) / denom;
        partial[blk] = tot * wgt * (1.0f / (float)(BB * NN * TT));
    }
}

__global__ __launch_bounds__(64) void reduce_kernel(
    const float* __restrict__ partial, float* __restrict__ out)
{
    const int tid = threadIdx.x;
    float s = 0.0f;
    for (int i = tid; i < BB * TT; i += 64) s += partial[i];
    #pragma unroll
    for (int off = 32; off > 0; off >>= 1)
        s += __shfl_down(s, off, 64);
    if (tid == 0) out[0] = s;
}

extern "C" void kernel_launch(void* const* d_in, const int* in_sizes, int n_in,
                              void* d_out, int out_size, void* d_ws, size_t ws_size,
                              hipStream_t stream) {
    const float* Y      = (const float*)d_in[0];
    const float* length = (const float*)d_in[1];
    const float* width  = (const float*)d_in[2];
    float* out = (float*)d_out;
    float* partial = (float*)d_ws;  // needs BB*TT*4 = 1280 bytes

    collision_kernel<<<BB * TT, 256, 0, stream>>>(Y, length, width, partial);
    reduce_kernel<<<1, 64, 0, stream>>>(partial, out);
}